// Round 5
// baseline (238.860 us; speedup 1.0000x reference)
//
#include <hip/hip_runtime.h>
#include <hip/hip_bf16.h>

typedef float f32x4 __attribute__((ext_vector_type(4)));
typedef __bf16 bf16x8 __attribute__((ext_vector_type(8)));

#define MFMA(a,b,c) __builtin_amdgcn_mfma_f32_16x16x32_bf16(a,b,c,0,0,0)

// workspace layout (bytes)
#define WS_A_BF   0x000000   // bf16 8192*128  (h@W1a + edge_b1), row-major [node][fi]
#define WS_B_BF   0x200000   // bf16 8192*128  (h@W1b), frag-chunk: [t][fi8][c][8]
#define WS_W2F    0x400000   // bf16 128*128   edge_w2  frag-major [(ks*8+nt)*512+lane*8+j]
#define WS_C1F    0x408000   // bf16 128*128   coord_w1 frag-major
#define WS_W1AT   0x410000   // bf16 128*128   edge_w1[0:128]^T   [out][in]
#define WS_W1BT   0x418000   // bf16 128*128   edge_w1[128:256]^T [out][in]
#define WS_VW1T   0x420000   // bf16 128*128   velm_w1^T
#define WS_MW2T   0x428000   // bf16 128*128   mlp_w2^T
#define WS_EWT    0x430000   // bf16 128*32    embed_w^T (K padded 30->32)
#define WS_MW1T   0x432000   // bf16 128*64    mlp_w1^T  (K padded 34->64)
#define WS_W1S    0x436000   // bf16 128       edge_w1 row256+row257
#define WS_BASE   0x436200   // f32 8192*2     vel_scale*vel + zMLP

// fast silu: v_exp + v_rcp
static __device__ __forceinline__ float silu_f(float x) {
  float e = __expf(-x);
  return x * __builtin_amdgcn_rcpf(1.0f + e);
}

// ---------------- kernel 0: weight prep --------------------------------------
__global__ void k_prep(const float* __restrict__ ew1, const float* __restrict__ ew2,
                       const float* __restrict__ cw1, const float* __restrict__ vw1,
                       const float* __restrict__ mw1, const float* __restrict__ mw2,
                       const float* __restrict__ embw, char* __restrict__ ws) {
  int n = blockIdx.x;   // fo 0..127
  int k = threadIdx.x;  // fi 0..127
  // frag-major index: one 16x32 B-fragment = 512 elements (64 lanes x 8)
  int ks = k >> 5, lgrp = (k >> 3) & 3, j = k & 7, nt = n >> 4, lid = n & 15;
  int fidx = (ks*8 + nt)*512 + (lgrp*16 + lid)*8 + j;
  ((__bf16*)(ws+WS_W2F))[fidx] = (__bf16)ew2[k*128+n];
  ((__bf16*)(ws+WS_C1F))[fidx] = (__bf16)cw1[k*128+n];
  ((__bf16*)(ws+WS_W1AT))[n*128+k] = (__bf16)ew1[k*128+n];
  ((__bf16*)(ws+WS_W1BT))[n*128+k] = (__bf16)ew1[(128+k)*128+n];
  ((__bf16*)(ws+WS_VW1T))[n*128+k] = (__bf16)vw1[k*128+n];
  ((__bf16*)(ws+WS_MW2T))[n*128+k] = (__bf16)mw2[k*128+n];
  if (k < 32) ((__bf16*)(ws+WS_EWT ))[n*32+k] = (k<30) ? (__bf16)embw[k*128+n] : (__bf16)0.0f;
  if (k < 64) ((__bf16*)(ws+WS_MW1T))[n*64+k] = (k<34) ? (__bf16)mw1[k*128+n] : (__bf16)0.0f;
  if (n == 0) ((__bf16*)(ws+WS_W1S))[k] = (__bf16)(ew1[256*128+k] + ew1[257*128+k]);
}

// ---------------- kernel 1: node-level (h, A_pre, B_pre, vel_scale, zMLP) -----
__global__ __launch_bounds__(256) void k_node(
    const float* __restrict__ obs,
    const float* __restrict__ emb_b,   const float* __restrict__ edge_b1,
    const float* __restrict__ velm_b1, const float* __restrict__ velm_w2,
    const float* __restrict__ velm_b2, const float* __restrict__ mlp_b1,
    const float* __restrict__ mlp_b2,  const float* __restrict__ mlp_w3,
    const float* __restrict__ mlp_b3,  char* __restrict__ ws) {
  __shared__ char hsh_all[4*4096];
  const int tid = threadIdx.x;
  const int wid = tid>>6, lane = tid&63, lgrp = lane>>4, lid = lane&15;
  char* hw = hsh_all + wid*4096;   // 16 rows x 256B per wave
  const int nb = blockIdx.x*64 + wid*16;
  const int node = nb + lid;

  const __bf16* EWT  = (const __bf16*)(ws+WS_EWT);
  const __bf16* W1AT = (const __bf16*)(ws+WS_W1AT);
  const __bf16* W1BT = (const __bf16*)(ws+WS_W1BT);
  const __bf16* VW1T = (const __bf16*)(ws+WS_VW1T);
  const __bf16* MW1T = (const __bf16*)(ws+WS_MW1T);
  const __bf16* MW2T = (const __bf16*)(ws+WS_MW2T);
  __bf16* A_bf = (__bf16*)(ws+WS_A_BF);
  __bf16* B_bf = (__bf16*)(ws+WS_B_BF);
  float* baseo = (float*)(ws+WS_BASE);

  f32x4 acc[8];

  // ---- stage 1: h = h_in @ embed_w + emb_b (K=32 padded) ----
  bf16x8 aobs;
  #pragma unroll
  for (int j = 0; j < 8; ++j) {
    int k = lgrp*8 + j;
    aobs[j] = (k < 30) ? (__bf16)obs[node*34 + 4 + k] : (__bf16)0.0f;
  }
  #pragma unroll
  for (int nt = 0; nt < 8; ++nt) acc[nt] = (f32x4){0.f,0.f,0.f,0.f};
  #pragma unroll
  for (int nt = 0; nt < 8; ++nt) {
    bf16x8 bw = *(const bf16x8*)(EWT + (nt*16+lid)*32 + lgrp*8);
    acc[nt] = MFMA(aobs, bw, acc[nt]);
  }
  #pragma unroll
  for (int nt = 0; nt < 8; ++nt) {
    int col = nt*16 + lid;
    #pragma unroll
    for (int e = 0; e < 4; ++e) {
      int rl = lgrp*4 + e;
      *(__bf16*)(hw + rl*256 + ((col*2) ^ ((rl&7)<<4))) = (__bf16)(acc[nt][e] + emb_b[col]);
    }
  }
  bf16x8 ah[4];
  #pragma unroll
  for (int ks = 0; ks < 4; ++ks)
    ah[ks] = *(const bf16x8*)(hw + lid*256 + ((ks*64 + lgrp*16) ^ ((lid&7)<<4)));

  // ---- stage 2: A_pre = h @ W1a + edge_b1 -> ws (bf16, row-major) ----
  #pragma unroll
  for (int nt = 0; nt < 8; ++nt) acc[nt] = (f32x4){0.f,0.f,0.f,0.f};
  #pragma unroll
  for (int ks = 0; ks < 4; ++ks)
    #pragma unroll
    for (int nt = 0; nt < 8; ++nt) {
      bf16x8 bw = *(const bf16x8*)(W1AT + (nt*16+lid)*128 + ks*32 + lgrp*8);
      acc[nt] = MFMA(ah[ks], bw, acc[nt]);
    }
  #pragma unroll
  for (int nt = 0; nt < 8; ++nt) {
    int col = nt*16 + lid;
    #pragma unroll
    for (int e = 0; e < 4; ++e)
      A_bf[(nb + lgrp*4 + e)*128 + col] = (__bf16)(acc[nt][e] + edge_b1[col]);
  }

  // ---- stage 3: B_pre = h @ W1b -> ws (bf16, frag-chunk layout) ----
  #pragma unroll
  for (int nt = 0; nt < 8; ++nt) acc[nt] = (f32x4){0.f,0.f,0.f,0.f};
  #pragma unroll
  for (int ks = 0; ks < 4; ++ks)
    #pragma unroll
    for (int nt = 0; nt < 8; ++nt) {
      bf16x8 bw = *(const bf16x8*)(W1BT + (nt*16+lid)*128 + ks*32 + lgrp*8);
      acc[nt] = MFMA(ah[ks], bw, acc[nt]);
    }
  {
    const int t = blockIdx.x;     // 64 nodes per block == one t
    #pragma unroll
    for (int nt = 0; nt < 8; ++nt) {
      int chunk = nt*2 + (lid>>3), j = lid & 7;
      #pragma unroll
      for (int e = 0; e < 4; ++e) {
        int c = wid*16 + lgrp*4 + e;
        B_bf[(size_t)t*8192 + chunk*512 + c*8 + j] = (__bf16)acc[nt][e];
      }
    }
  }

  // ---- stage 4: vel_scale = silu(h@velm_w1 + b1) @ velm_w2 + b2 ----
  #pragma unroll
  for (int nt = 0; nt < 8; ++nt) acc[nt] = (f32x4){0.f,0.f,0.f,0.f};
  #pragma unroll
  for (int ks = 0; ks < 4; ++ks)
    #pragma unroll
    for (int nt = 0; nt < 8; ++nt) {
      bf16x8 bw = *(const bf16x8*)(VW1T + (nt*16+lid)*128 + ks*32 + lgrp*8);
      acc[nt] = MFMA(ah[ks], bw, acc[nt]);
    }
  float pv[4] = {0.f,0.f,0.f,0.f};
  #pragma unroll
  for (int nt = 0; nt < 8; ++nt) {
    int col = nt*16 + lid;
    float w2 = velm_w2[col], b = velm_b1[col];
    #pragma unroll
    for (int e = 0; e < 4; ++e) pv[e] += silu_f(acc[nt][e] + b) * w2;
  }
  #pragma unroll
  for (int d = 1; d < 16; d <<= 1) {
    #pragma unroll
    for (int e = 0; e < 4; ++e) pv[e] += __shfl_xor(pv[e], d, 64);
  }
  float vs[4];
  #pragma unroll
  for (int e = 0; e < 4; ++e) vs[e] = pv[e] + velm_b2[0];

  // ---- stage 5: z1 = silu(obs @ mlp_w1 + b1) (K=64 padded) ----
  bf16x8 az[2];
  #pragma unroll
  for (int ks2 = 0; ks2 < 2; ++ks2)
    #pragma unroll
    for (int j = 0; j < 8; ++j) {
      int k = ks2*32 + lgrp*8 + j;
      az[ks2][j] = (k < 34) ? (__bf16)obs[node*34 + k] : (__bf16)0.0f;
    }
  #pragma unroll
  for (int nt = 0; nt < 8; ++nt) acc[nt] = (f32x4){0.f,0.f,0.f,0.f};
  #pragma unroll
  for (int ks2 = 0; ks2 < 2; ++ks2)
    #pragma unroll
    for (int nt = 0; nt < 8; ++nt) {
      bf16x8 bw = *(const bf16x8*)(MW1T + (nt*16+lid)*64 + ks2*32 + lgrp*8);
      acc[nt] = MFMA(az[ks2], bw, acc[nt]);
    }
  #pragma unroll
  for (int nt = 0; nt < 8; ++nt) {
    int col = nt*16 + lid;
    float b = mlp_b1[col];
    #pragma unroll
    for (int e = 0; e < 4; ++e) {
      int rl = lgrp*4 + e;
      *(__bf16*)(hw + rl*256 + ((col*2) ^ ((rl&7)<<4))) = (__bf16)silu_f(acc[nt][e] + b);
    }
  }
  bf16x8 az1[4];
  #pragma unroll
  for (int ks = 0; ks < 4; ++ks)
    az1[ks] = *(const bf16x8*)(hw + lid*256 + ((ks*64 + lgrp*16) ^ ((lid&7)<<4)));

  // ---- stage 6: z2 = silu(z1@mlp_w2 + b2); o = z2@mlp_w3 ----
  #pragma unroll
  for (int nt = 0; nt < 8; ++nt) acc[nt] = (f32x4){0.f,0.f,0.f,0.f};
  #pragma unroll
  for (int ks = 0; ks < 4; ++ks)
    #pragma unroll
    for (int nt = 0; nt < 8; ++nt) {
      bf16x8 bw = *(const bf16x8*)(MW2T + (nt*16+lid)*128 + ks*32 + lgrp*8);
      acc[nt] = MFMA(az1[ks], bw, acc[nt]);
    }
  float p0[4] = {0.f,0.f,0.f,0.f}, p1[4] = {0.f,0.f,0.f,0.f};
  #pragma unroll
  for (int nt = 0; nt < 8; ++nt) {
    int col = nt*16 + lid;
    float b = mlp_b2[col], w0 = mlp_w3[col*2], w1 = mlp_w3[col*2+1];
    #pragma unroll
    for (int e = 0; e < 4; ++e) {
      float z2 = silu_f(acc[nt][e] + b);
      p0[e] += z2*w0; p1[e] += z2*w1;
    }
  }
  #pragma unroll
  for (int d = 1; d < 16; d <<= 1) {
    #pragma unroll
    for (int e = 0; e < 4; ++e) { p0[e] += __shfl_xor(p0[e], d, 64); p1[e] += __shfl_xor(p1[e], d, 64); }
  }

  // ---- stage 7: base = vel_scale*vel + zMLP out ----
  if (lid == 0) {
    #pragma unroll
    for (int e = 0; e < 4; ++e) {
      int row = nb + lgrp*4 + e;
      float v0 = obs[row*34+2], v1 = obs[row*34+3];
      baseo[row*2+0] = vs[e]*v0 + p0[e] + mlp_b3[0];
      baseo[row*2+1] = vs[e]*v1 + p1[e] + mlp_b3[1];
    }
  }
}

// ---------------- kernel 2: edge chain + aggregation + output -----------------
// 2048 blocks x 256 threads (4 waves). Wave w: r = t*64 + rblk*4 + w vs all 64
// c, as 2 halves of 32-edge M-tiles. ALL loads (weights, B) are coalesced
// frag-major global reads (L1/L2-hot); no Bsh, NO BARRIERS. msh per-wave.
__global__ __launch_bounds__(256, 3) void k_edge(
    const float* __restrict__ obs, const float* __restrict__ eps,
    const float* __restrict__ edge_b2, const float* __restrict__ coord_b1,
    const float* __restrict__ coord_w2, const float* __restrict__ coord_b2,
    const float* __restrict__ log_std,
    const char* __restrict__ ws, float* __restrict__ out) {
  __shared__ __align__(16) char msh_all[4*8192]; // per-wave 32 rows x 256B
  __shared__ float locsh[128];
  __shared__ __align__(16) unsigned short wssh[128]; // w1s bf16
  __shared__ float b2sh[128], cb1sh[128], c2sh[128];
  const int tid = threadIdx.x;
  const int wid = tid>>6, lane = tid&63, lgrp = lane>>4, lid = lane&15;
  const int t = blockIdx.x >> 4, rblk = blockIdx.x & 15;
  const int rl = rblk*4 + wid;
  const int r  = t*64 + rl;
  char* msh = msh_all + wid*8192;

  const __bf16* A_bf = (const __bf16*)(ws+WS_A_BF);
  const __bf16* Bt   = (const __bf16*)(ws+WS_B_BF) + (size_t)t*8192;
  const __bf16* W2F  = (const __bf16*)(ws+WS_W2F);
  const __bf16* C1F  = (const __bf16*)(ws+WS_C1F);
  const float* baseo = (const float*)(ws+WS_BASE);

  // per-wave redundant staging (identical values -> benign races, no barrier)
  {
    int node = t*64 + lane;
    locsh[lane*2+0] = obs[(size_t)node*34 + 0];
    locsh[lane*2+1] = obs[(size_t)node*34 + 1];
    const unsigned short* w1su = (const unsigned short*)(ws+WS_W1S);
    wssh[lane]    = w1su[lane];    wssh[lane+64]  = w1su[lane+64];
    b2sh[lane]    = edge_b2[lane]; b2sh[lane+64]  = edge_b2[lane+64];
    cb1sh[lane]   = coord_b1[lane];cb1sh[lane+64] = coord_b1[lane+64];
    c2sh[lane]    = coord_w2[lane];c2sh[lane+64]  = coord_w2[lane+64];
  }

  bf16x8 aA[4];
  #pragma unroll
  for (int ks = 0; ks < 4; ++ks)
    aA[ks] = *(const bf16x8*)(A_bf + (size_t)r*128 + ks*32 + lgrp*8);
  const float cb2 = coord_b2[0];
  const float lr0 = locsh[rl*2], lr1 = locsh[rl*2+1];

  float agg0 = 0.f, agg1 = 0.f;

  #pragma unroll 1
  for (int half = 0; half < 2; ++half) {
    const int c0 = half*32;
    float rad[2];
    #pragma unroll
    for (int mt = 0; mt < 2; ++mt) {
      int c = c0 + mt*16 + lid;
      float d0 = lr0 - locsh[c*2], d1 = lr1 - locsh[c*2+1];
      rad[mt] = d0*d0 + d1*d1;
    }

    f32x4 acc[2][8];
    #pragma unroll
    for (int mt = 0; mt < 2; ++mt)
      #pragma unroll
      for (int nt = 0; nt < 8; ++nt) acc[mt][nt] = (f32x4){0.f,0.f,0.f,0.f};

    // GEMM1 (ks-outer): a1 just-in-time; all loads coalesced
    #pragma unroll 1
    for (int ks = 0; ks < 4; ++ks) {
      bf16x8 wsv = *(const bf16x8*)((const char*)wssh + ks*64 + lgrp*16);
      bf16x8 a1[2];
      #pragma unroll
      for (int mt = 0; mt < 2; ++mt) {
        int c = c0 + mt*16 + lid;
        bf16x8 bv = *(const bf16x8*)(Bt + (ks*4+lgrp)*512 + c*8);
        bf16x8 o;
        #pragma unroll
        for (int j = 0; j < 8; ++j) {
          float f = (float)aA[ks][j] + (float)bv[j] + rad[mt]*(float)wsv[j];
          o[j] = (__bf16)silu_f(f);
        }
        a1[mt] = o;
      }
      #pragma unroll
      for (int nt = 0; nt < 8; ++nt) {
        bf16x8 bw = *(const bf16x8*)(W2F + (ks*8+nt)*512 + lane*8);
        acc[0][nt] = MFMA(a1[0], bw, acc[0][nt]);
        acc[1][nt] = MFMA(a1[1], bw, acc[1][nt]);
      }
    }

    // silu + write to per-wave LDS (transpose to A-frag layout for GEMM2)
    #pragma unroll
    for (int nt = 0; nt < 8; ++nt) {
      int col = nt*16 + lid;
      float b = b2sh[col];
      #pragma unroll
      for (int mt = 0; mt < 2; ++mt)
        #pragma unroll
        for (int e = 0; e < 4; ++e) {
          int rlo = mt*16 + lgrp*4 + e;
          *(__bf16*)(msh + rlo*256 + ((col*2) ^ ((rlo&7)<<4))) =
              (__bf16)silu_f(acc[mt][nt][e] + b);
        }
    }

    #pragma unroll
    for (int mt = 0; mt < 2; ++mt)
      #pragma unroll
      for (int nt = 0; nt < 8; ++nt) acc[mt][nt] = (f32x4){0.f,0.f,0.f,0.f};

    // GEMM2 (ks-outer): a2 just-in-time from msh; weights coalesced
    #pragma unroll 1
    for (int ks = 0; ks < 4; ++ks) {
      bf16x8 a2[2];
      #pragma unroll
      for (int mt = 0; mt < 2; ++mt) {
        int rlo = mt*16 + lid;
        a2[mt] = *(const bf16x8*)(msh + rlo*256 + ((ks*64 + lgrp*16) ^ ((rlo&7)<<4)));
      }
      #pragma unroll
      for (int nt = 0; nt < 8; ++nt) {
        bf16x8 bw = *(const bf16x8*)(C1F + (ks*8+nt)*512 + lane*8);
        acc[0][nt] = MFMA(a2[0], bw, acc[0][nt]);
        acc[1][nt] = MFMA(a2[1], bw, acc[1][nt]);
      }
    }

    // epilogue: cw = silu(tc + cb1) . c2 + cb2 ; aggregate diff*cw
    float pcw[2][4];
    #pragma unroll
    for (int mt = 0; mt < 2; ++mt)
      #pragma unroll
      for (int e = 0; e < 4; ++e) pcw[mt][e] = 0.f;
    #pragma unroll
    for (int nt = 0; nt < 8; ++nt) {
      int col = nt*16 + lid;
      float cb1 = cb1sh[col], c2 = c2sh[col];
      #pragma unroll
      for (int mt = 0; mt < 2; ++mt)
        #pragma unroll
        for (int e = 0; e < 4; ++e)
          pcw[mt][e] += silu_f(acc[mt][nt][e] + cb1) * c2;
    }
    #pragma unroll
    for (int d = 1; d < 16; d <<= 1) {
      #pragma unroll
      for (int mt = 0; mt < 2; ++mt)
        #pragma unroll
        for (int e = 0; e < 4; ++e) pcw[mt][e] += __shfl_xor(pcw[mt][e], d, 64);
    }
    #pragma unroll
    for (int mt = 0; mt < 2; ++mt)
      #pragma unroll
      for (int e = 0; e < 4; ++e) {
        int ce = c0 + mt*16 + lgrp*4 + e;
        float cw = pcw[mt][e] + cb2;
        float e0 = lr0 - locsh[ce*2], e1 = lr1 - locsh[ce*2+1];
        float r2 = e0*e0 + e1*e1;
        float s = cw * __builtin_amdgcn_rcpf(__builtin_amdgcn_sqrtf(r2) + 1.0f);
        agg0 += e0*s; agg1 += e1*s;
      }
  }
  // sum partials across the four 16-lane groups
  agg0 += __shfl_xor(agg0, 16, 64); agg0 += __shfl_xor(agg0, 32, 64);
  agg1 += __shfl_xor(agg1, 16, 64); agg1 += __shfl_xor(agg1, 32, 64);

  if (lane == 0) {
    float mu0 = baseo[r*2+0] + agg0;
    float mu1 = baseo[r*2+1] + agg1;
    float ls0 = log_std[0], ls1 = log_std[1];
    float e0 = eps[r*2+0], e1 = eps[r*2+1];
    const float C = 0.9189385332046727f; // 0.5*log(2*pi)
    out[r*4+0] = mu0 + __expf(ls0)*e0;
    out[r*4+1] = mu1 + __expf(ls1)*e1;
    out[r*4+2] = -0.5f*e0*e0 - ls0 - C;
    out[r*4+3] = -0.5f*e1*e1 - ls1 - C;
  }
}

extern "C" void kernel_launch(void* const* d_in, const int* in_sizes, int n_in,
                              void* d_out, int out_size, void* d_ws, size_t ws_size,
                              hipStream_t stream) {
  const float* obs      = (const float*)d_in[0];
  const float* eps      = (const float*)d_in[1];
  const float* embed_w  = (const float*)d_in[2];
  const float* embed_b  = (const float*)d_in[3];
  const float* edge_w1  = (const float*)d_in[4];
  const float* edge_b1  = (const float*)d_in[5];
  const float* edge_w2  = (const float*)d_in[6];
  const float* edge_b2  = (const float*)d_in[7];
  const float* coord_w1 = (const float*)d_in[8];
  const float* coord_b1 = (const float*)d_in[9];
  const float* coord_w2 = (const float*)d_in[10];
  const float* coord_b2 = (const float*)d_in[11];
  const float* velm_w1  = (const float*)d_in[12];
  const float* velm_b1  = (const float*)d_in[13];
  const float* velm_w2  = (const float*)d_in[14];
  const float* velm_b2  = (const float*)d_in[15];
  const float* mlp_w1   = (const float*)d_in[20];
  const float* mlp_b1   = (const float*)d_in[21];
  const float* mlp_w2   = (const float*)d_in[22];
  const float* mlp_b2   = (const float*)d_in[23];
  const float* mlp_w3   = (const float*)d_in[24];
  const float* mlp_b3   = (const float*)d_in[25];
  const float* log_std  = (const float*)d_in[26];
  char* ws = (char*)d_ws;
  float* out = (float*)d_out;

  hipLaunchKernelGGL(k_prep, dim3(128), dim3(128), 0, stream,
                     edge_w1, edge_w2, coord_w1, velm_w1, mlp_w1, mlp_w2, embed_w, ws);
  hipLaunchKernelGGL(k_node, dim3(128), dim3(256), 0, stream,
                     obs, embed_b, edge_b1, velm_b1, velm_w2, velm_b2,
                     mlp_b1, mlp_b2, mlp_w3, mlp_b3, ws);
  hipLaunchKernelGGL(k_edge, dim3(2048), dim3(256), 0, stream,
                     obs, eps, edge_b2, coord_b1, coord_w2, coord_b2, log_std, ws, out);
}

// Round 6
// 195.411 us; speedup vs baseline: 1.2223x; 1.2223x over previous
//
#include <hip/hip_runtime.h>
#include <hip/hip_bf16.h>

typedef float f32x4 __attribute__((ext_vector_type(4)));
typedef __bf16 bf16x8 __attribute__((ext_vector_type(8)));

#define MFMA(a,b,c) __builtin_amdgcn_mfma_f32_16x16x32_bf16(a,b,c,0,0,0)

// workspace layout (bytes)
#define WS_A_BF   0x000000   // bf16 8192*128  (h@W1a + edge_b1), row-major [node][fi]
#define WS_B_BF   0x200000   // bf16 8192*128  (h@W1b), frag-chunk: [t][fi8][c][8]
#define WS_W2F    0x400000   // bf16 128*128   edge_w2  frag-major [(ks*8+nt)*512+lane*8+j]
#define WS_C1F    0x408000   // bf16 128*128   coord_w1 frag-major (contiguous after W2F)
#define WS_W1AT   0x410000   // bf16 128*128   edge_w1[0:128]^T   [out][in]
#define WS_W1BT   0x418000   // bf16 128*128   edge_w1[128:256]^T [out][in]
#define WS_VW1T   0x420000   // bf16 128*128   velm_w1^T
#define WS_MW2T   0x428000   // bf16 128*128   mlp_w2^T
#define WS_EWT    0x430000   // bf16 128*32    embed_w^T (K padded 30->32)
#define WS_MW1T   0x432000   // bf16 128*64    mlp_w1^T  (K padded 34->64)
#define WS_W1S    0x436000   // bf16 128       edge_w1 row256+row257
#define WS_BASE   0x436200   // f32 8192*2     vel_scale*vel + zMLP

// k_edge dynamic-LDS layout (bytes)
#define L_WGT   0        // 65536: W2F(32K) + C1F(32K), frag-major
#define L_MSH   65536    // 65536: 8 waves x 8192
#define L_LOC   131072   // 512:   loc f32[128]
#define L_B2    131584   // 512
#define L_CB1   132096   // 512
#define L_C2    132608   // 512
#define L_WSS   133120   // 256:   w1s bf16[128]
#define L_TOTAL 133376

// fast silu: v_exp + v_rcp
static __device__ __forceinline__ float silu_f(float x) {
  float e = __expf(-x);
  return x * __builtin_amdgcn_rcpf(1.0f + e);
}

// ---------------- kernel 0: weight prep --------------------------------------
__global__ void k_prep(const float* __restrict__ ew1, const float* __restrict__ ew2,
                       const float* __restrict__ cw1, const float* __restrict__ vw1,
                       const float* __restrict__ mw1, const float* __restrict__ mw2,
                       const float* __restrict__ embw, char* __restrict__ ws) {
  int n = blockIdx.x;   // fo 0..127
  int k = threadIdx.x;  // fi 0..127
  // frag-major index: one 16x32 B-fragment = 512 elements (64 lanes x 8)
  int ks = k >> 5, lgrp = (k >> 3) & 3, j = k & 7, nt = n >> 4, lid = n & 15;
  int fidx = (ks*8 + nt)*512 + (lgrp*16 + lid)*8 + j;
  ((__bf16*)(ws+WS_W2F))[fidx] = (__bf16)ew2[k*128+n];
  ((__bf16*)(ws+WS_C1F))[fidx] = (__bf16)cw1[k*128+n];
  ((__bf16*)(ws+WS_W1AT))[n*128+k] = (__bf16)ew1[k*128+n];
  ((__bf16*)(ws+WS_W1BT))[n*128+k] = (__bf16)ew1[(128+k)*128+n];
  ((__bf16*)(ws+WS_VW1T))[n*128+k] = (__bf16)vw1[k*128+n];
  ((__bf16*)(ws+WS_MW2T))[n*128+k] = (__bf16)mw2[k*128+n];
  if (k < 32) ((__bf16*)(ws+WS_EWT ))[n*32+k] = (k<30) ? (__bf16)embw[k*128+n] : (__bf16)0.0f;
  if (k < 64) ((__bf16*)(ws+WS_MW1T))[n*64+k] = (k<34) ? (__bf16)mw1[k*128+n] : (__bf16)0.0f;
  if (n == 0) ((__bf16*)(ws+WS_W1S))[k] = (__bf16)(ew1[256*128+k] + ew1[257*128+k]);
}

// ---------------- kernel 1: node-level (h, A_pre, B_pre, vel_scale, zMLP) -----
__global__ __launch_bounds__(256) void k_node(
    const float* __restrict__ obs,
    const float* __restrict__ emb_b,   const float* __restrict__ edge_b1,
    const float* __restrict__ velm_b1, const float* __restrict__ velm_w2,
    const float* __restrict__ velm_b2, const float* __restrict__ mlp_b1,
    const float* __restrict__ mlp_b2,  const float* __restrict__ mlp_w3,
    const float* __restrict__ mlp_b3,  char* __restrict__ ws) {
  __shared__ char hsh_all[4*4096];
  const int tid = threadIdx.x;
  const int wid = tid>>6, lane = tid&63, lgrp = lane>>4, lid = lane&15;
  char* hw = hsh_all + wid*4096;   // 16 rows x 256B per wave
  const int nb = blockIdx.x*64 + wid*16;
  const int node = nb + lid;

  const __bf16* EWT  = (const __bf16*)(ws+WS_EWT);
  const __bf16* W1AT = (const __bf16*)(ws+WS_W1AT);
  const __bf16* W1BT = (const __bf16*)(ws+WS_W1BT);
  const __bf16* VW1T = (const __bf16*)(ws+WS_VW1T);
  const __bf16* MW1T = (const __bf16*)(ws+WS_MW1T);
  const __bf16* MW2T = (const __bf16*)(ws+WS_MW2T);
  __bf16* A_bf = (__bf16*)(ws+WS_A_BF);
  __bf16* B_bf = (__bf16*)(ws+WS_B_BF);
  float* baseo = (float*)(ws+WS_BASE);

  f32x4 acc[8];

  // ---- stage 1: h = h_in @ embed_w + emb_b (K=32 padded) ----
  bf16x8 aobs;
  #pragma unroll
  for (int j = 0; j < 8; ++j) {
    int k = lgrp*8 + j;
    aobs[j] = (k < 30) ? (__bf16)obs[node*34 + 4 + k] : (__bf16)0.0f;
  }
  #pragma unroll
  for (int nt = 0; nt < 8; ++nt) acc[nt] = (f32x4){0.f,0.f,0.f,0.f};
  #pragma unroll
  for (int nt = 0; nt < 8; ++nt) {
    bf16x8 bw = *(const bf16x8*)(EWT + (nt*16+lid)*32 + lgrp*8);
    acc[nt] = MFMA(aobs, bw, acc[nt]);
  }
  #pragma unroll
  for (int nt = 0; nt < 8; ++nt) {
    int col = nt*16 + lid;
    #pragma unroll
    for (int e = 0; e < 4; ++e) {
      int rl = lgrp*4 + e;
      *(__bf16*)(hw + rl*256 + ((col*2) ^ ((rl&7)<<4))) = (__bf16)(acc[nt][e] + emb_b[col]);
    }
  }
  bf16x8 ah[4];
  #pragma unroll
  for (int ks = 0; ks < 4; ++ks)
    ah[ks] = *(const bf16x8*)(hw + lid*256 + ((ks*64 + lgrp*16) ^ ((lid&7)<<4)));

  // ---- stage 2: A_pre = h @ W1a + edge_b1 -> ws (bf16, row-major) ----
  #pragma unroll
  for (int nt = 0; nt < 8; ++nt) acc[nt] = (f32x4){0.f,0.f,0.f,0.f};
  #pragma unroll
  for (int ks = 0; ks < 4; ++ks)
    #pragma unroll
    for (int nt = 0; nt < 8; ++nt) {
      bf16x8 bw = *(const bf16x8*)(W1AT + (nt*16+lid)*128 + ks*32 + lgrp*8);
      acc[nt] = MFMA(ah[ks], bw, acc[nt]);
    }
  #pragma unroll
  for (int nt = 0; nt < 8; ++nt) {
    int col = nt*16 + lid;
    #pragma unroll
    for (int e = 0; e < 4; ++e)
      A_bf[(nb + lgrp*4 + e)*128 + col] = (__bf16)(acc[nt][e] + edge_b1[col]);
  }

  // ---- stage 3: B_pre = h @ W1b -> ws (bf16, frag-chunk layout) ----
  #pragma unroll
  for (int nt = 0; nt < 8; ++nt) acc[nt] = (f32x4){0.f,0.f,0.f,0.f};
  #pragma unroll
  for (int ks = 0; ks < 4; ++ks)
    #pragma unroll
    for (int nt = 0; nt < 8; ++nt) {
      bf16x8 bw = *(const bf16x8*)(W1BT + (nt*16+lid)*128 + ks*32 + lgrp*8);
      acc[nt] = MFMA(ah[ks], bw, acc[nt]);
    }
  {
    const int t = blockIdx.x;     // 64 nodes per block == one t
    #pragma unroll
    for (int nt = 0; nt < 8; ++nt) {
      int chunk = nt*2 + (lid>>3), j = lid & 7;
      #pragma unroll
      for (int e = 0; e < 4; ++e) {
        int c = wid*16 + lgrp*4 + e;
        B_bf[(size_t)t*8192 + chunk*512 + c*8 + j] = (__bf16)acc[nt][e];
      }
    }
  }

  // ---- stage 4: vel_scale = silu(h@velm_w1 + b1) @ velm_w2 + b2 ----
  #pragma unroll
  for (int nt = 0; nt < 8; ++nt) acc[nt] = (f32x4){0.f,0.f,0.f,0.f};
  #pragma unroll
  for (int ks = 0; ks < 4; ++ks)
    #pragma unroll
    for (int nt = 0; nt < 8; ++nt) {
      bf16x8 bw = *(const bf16x8*)(VW1T + (nt*16+lid)*128 + ks*32 + lgrp*8);
      acc[nt] = MFMA(ah[ks], bw, acc[nt]);
    }
  float pv[4] = {0.f,0.f,0.f,0.f};
  #pragma unroll
  for (int nt = 0; nt < 8; ++nt) {
    int col = nt*16 + lid;
    float w2 = velm_w2[col], b = velm_b1[col];
    #pragma unroll
    for (int e = 0; e < 4; ++e) pv[e] += silu_f(acc[nt][e] + b) * w2;
  }
  #pragma unroll
  for (int d = 1; d < 16; d <<= 1) {
    #pragma unroll
    for (int e = 0; e < 4; ++e) pv[e] += __shfl_xor(pv[e], d, 64);
  }
  float vs[4];
  #pragma unroll
  for (int e = 0; e < 4; ++e) vs[e] = pv[e] + velm_b2[0];

  // ---- stage 5: z1 = silu(obs @ mlp_w1 + b1) (K=64 padded) ----
  bf16x8 az[2];
  #pragma unroll
  for (int ks2 = 0; ks2 < 2; ++ks2)
    #pragma unroll
    for (int j = 0; j < 8; ++j) {
      int k = ks2*32 + lgrp*8 + j;
      az[ks2][j] = (k < 34) ? (__bf16)obs[node*34 + k] : (__bf16)0.0f;
    }
  #pragma unroll
  for (int nt = 0; nt < 8; ++nt) acc[nt] = (f32x4){0.f,0.f,0.f,0.f};
  #pragma unroll
  for (int ks2 = 0; ks2 < 2; ++ks2)
    #pragma unroll
    for (int nt = 0; nt < 8; ++nt) {
      bf16x8 bw = *(const bf16x8*)(MW1T + (nt*16+lid)*64 + ks2*32 + lgrp*8);
      acc[nt] = MFMA(az[ks2], bw, acc[nt]);
    }
  #pragma unroll
  for (int nt = 0; nt < 8; ++nt) {
    int col = nt*16 + lid;
    float b = mlp_b1[col];
    #pragma unroll
    for (int e = 0; e < 4; ++e) {
      int rl = lgrp*4 + e;
      *(__bf16*)(hw + rl*256 + ((col*2) ^ ((rl&7)<<4))) = (__bf16)silu_f(acc[nt][e] + b);
    }
  }
  bf16x8 az1[4];
  #pragma unroll
  for (int ks = 0; ks < 4; ++ks)
    az1[ks] = *(const bf16x8*)(hw + lid*256 + ((ks*64 + lgrp*16) ^ ((lid&7)<<4)));

  // ---- stage 6: z2 = silu(z1@mlp_w2 + b2); o = z2@mlp_w3 ----
  #pragma unroll
  for (int nt = 0; nt < 8; ++nt) acc[nt] = (f32x4){0.f,0.f,0.f,0.f};
  #pragma unroll
  for (int ks = 0; ks < 4; ++ks)
    #pragma unroll
    for (int nt = 0; nt < 8; ++nt) {
      bf16x8 bw = *(const bf16x8*)(MW2T + (nt*16+lid)*128 + ks*32 + lgrp*8);
      acc[nt] = MFMA(az1[ks], bw, acc[nt]);
    }
  float p0[4] = {0.f,0.f,0.f,0.f}, p1[4] = {0.f,0.f,0.f,0.f};
  #pragma unroll
  for (int nt = 0; nt < 8; ++nt) {
    int col = nt*16 + lid;
    float b = mlp_b2[col], w0 = mlp_w3[col*2], w1 = mlp_w3[col*2+1];
    #pragma unroll
    for (int e = 0; e < 4; ++e) {
      float z2 = silu_f(acc[nt][e] + b);
      p0[e] += z2*w0; p1[e] += z2*w1;
    }
  }
  #pragma unroll
  for (int d = 1; d < 16; d <<= 1) {
    #pragma unroll
    for (int e = 0; e < 4; ++e) { p0[e] += __shfl_xor(p0[e], d, 64); p1[e] += __shfl_xor(p1[e], d, 64); }
  }

  // ---- stage 7: base = vel_scale*vel + zMLP out ----
  if (lid == 0) {
    #pragma unroll
    for (int e = 0; e < 4; ++e) {
      int row = nb + lgrp*4 + e;
      float v0 = obs[row*34+2], v1 = obs[row*34+3];
      baseo[row*2+0] = vs[e]*v0 + p0[e] + mlp_b3[0];
      baseo[row*2+1] = vs[e]*v1 + p1[e] + mlp_b3[1];
    }
  }
}

// ---------------- kernel 2: edge chain + aggregation + output -----------------
// 1024 blocks x 512 threads (8 waves). Block b: t = b>>3, wave w handles
// r = t*64 + (b&7)*8 + w vs all 64 c. BOTH weight matrices staged in dynamic
// LDS once per block (shared by 8 waves): weight reads are conflict-free
// ds_read_b128 instead of L1-thrashing global loads. One barrier total.
// (512,2): 256-reg budget -> unroll-2 ks loops give in-wave ILP.
__global__ __launch_bounds__(512, 2) void k_edge(
    const float* __restrict__ obs, const float* __restrict__ eps,
    const float* __restrict__ edge_b2, const float* __restrict__ coord_b1,
    const float* __restrict__ coord_w2, const float* __restrict__ coord_b2,
    const float* __restrict__ log_std,
    const char* __restrict__ ws, float* __restrict__ out) {
  extern __shared__ __align__(16) char lds[];
  const int tid = threadIdx.x;
  const int wid = tid>>6, lane = tid&63, lgrp = lane>>4, lid = lane&15;
  const int t = blockIdx.x >> 3, rgrp = blockIdx.x & 7;
  const int rl = rgrp*8 + wid;
  const int r  = t*64 + rl;
  char* msh = lds + L_MSH + wid*8192;
  float* locsh = (float*)(lds + L_LOC);
  float* b2sh  = (float*)(lds + L_B2);
  float* cb1sh = (float*)(lds + L_CB1);
  float* c2sh  = (float*)(lds + L_C2);

  const __bf16* A_bf = (const __bf16*)(ws+WS_A_BF);
  const __bf16* Bt   = (const __bf16*)(ws+WS_B_BF) + (size_t)t*8192;
  const float* baseo = (const float*)(ws+WS_BASE);

  // ---- stage weights (64KB, frag-major, contiguous W2F|C1F) + consts ----
  {
    const uint4* gw = (const uint4*)(ws+WS_W2F);
    uint4* lw = (uint4*)(lds + L_WGT);
    #pragma unroll
    for (int i = 0; i < 8; ++i) lw[tid + i*512] = gw[tid + i*512];
    if (tid < 128) {
      locsh[tid] = obs[(size_t)(t*64 + (tid>>1))*34 + (tid&1)];
      b2sh[tid]  = edge_b2[tid];
      cb1sh[tid] = coord_b1[tid];
      c2sh[tid]  = coord_w2[tid];
      ((unsigned short*)(lds+L_WSS))[tid] = ((const unsigned short*)(ws+WS_W1S))[tid];
    }
  }
  __syncthreads();

  const char* W2s = lds + L_WGT;           // 32 frags x 1KB
  const char* C1s = lds + L_WGT + 32768;
  const char* wss = lds + L_WSS;

  bf16x8 aA[4];
  #pragma unroll
  for (int ks = 0; ks < 4; ++ks)
    aA[ks] = *(const bf16x8*)(A_bf + (size_t)r*128 + ks*32 + lgrp*8);
  const float cb2 = coord_b2[0];
  const float lr0 = locsh[rl*2], lr1 = locsh[rl*2+1];

  float agg0 = 0.f, agg1 = 0.f;

  #pragma unroll 1
  for (int half = 0; half < 2; ++half) {
    const int c0 = half*32;
    float rad[2];
    #pragma unroll
    for (int mt = 0; mt < 2; ++mt) {
      int c = c0 + mt*16 + lid;
      float d0 = lr0 - locsh[c*2], d1 = lr1 - locsh[c*2+1];
      rad[mt] = d0*d0 + d1*d1;
    }

    f32x4 acc[2][8];
    #pragma unroll
    for (int mt = 0; mt < 2; ++mt)
      #pragma unroll
      for (int nt = 0; nt < 8; ++nt) acc[mt][nt] = (f32x4){0.f,0.f,0.f,0.f};

    // GEMM1: a1 just-in-time; weights from LDS (ds_read_b128)
    #pragma unroll 2
    for (int ks = 0; ks < 4; ++ks) {
      bf16x8 wsv = *(const bf16x8*)(wss + ks*64 + lgrp*16);
      bf16x8 a1[2];
      #pragma unroll
      for (int mt = 0; mt < 2; ++mt) {
        int c = c0 + mt*16 + lid;
        bf16x8 bv = *(const bf16x8*)(Bt + (ks*4+lgrp)*512 + c*8);
        bf16x8 o;
        #pragma unroll
        for (int j = 0; j < 8; ++j) {
          float f = (float)aA[ks][j] + (float)bv[j] + rad[mt]*(float)wsv[j];
          o[j] = (__bf16)silu_f(f);
        }
        a1[mt] = o;
      }
      #pragma unroll
      for (int nt = 0; nt < 8; ++nt) {
        bf16x8 bw = *(const bf16x8*)(W2s + ((ks*8+nt)*512 + lane*8)*2);
        acc[0][nt] = MFMA(a1[0], bw, acc[0][nt]);
        acc[1][nt] = MFMA(a1[1], bw, acc[1][nt]);
      }
    }

    // silu + write to per-wave LDS (transpose to A-frag layout for GEMM2)
    #pragma unroll
    for (int nt = 0; nt < 8; ++nt) {
      int col = nt*16 + lid;
      float b = b2sh[col];
      #pragma unroll
      for (int mt = 0; mt < 2; ++mt)
        #pragma unroll
        for (int e = 0; e < 4; ++e) {
          int rlo = mt*16 + lgrp*4 + e;
          *(__bf16*)(msh + rlo*256 + ((col*2) ^ ((rlo&7)<<4))) =
              (__bf16)silu_f(acc[mt][nt][e] + b);
        }
    }

    #pragma unroll
    for (int mt = 0; mt < 2; ++mt)
      #pragma unroll
      for (int nt = 0; nt < 8; ++nt) acc[mt][nt] = (f32x4){0.f,0.f,0.f,0.f};

    // GEMM2: a2 just-in-time from msh; weights from LDS
    #pragma unroll 2
    for (int ks = 0; ks < 4; ++ks) {
      bf16x8 a2[2];
      #pragma unroll
      for (int mt = 0; mt < 2; ++mt) {
        int rlo = mt*16 + lid;
        a2[mt] = *(const bf16x8*)(msh + rlo*256 + ((ks*64 + lgrp*16) ^ ((rlo&7)<<4)));
      }
      #pragma unroll
      for (int nt = 0; nt < 8; ++nt) {
        bf16x8 bw = *(const bf16x8*)(C1s + ((ks*8+nt)*512 + lane*8)*2);
        acc[0][nt] = MFMA(a2[0], bw, acc[0][nt]);
        acc[1][nt] = MFMA(a2[1], bw, acc[1][nt]);
      }
    }

    // epilogue: cw = silu(tc + cb1) . c2 + cb2 ; aggregate diff*cw
    float pcw[2][4];
    #pragma unroll
    for (int mt = 0; mt < 2; ++mt)
      #pragma unroll
      for (int e = 0; e < 4; ++e) pcw[mt][e] = 0.f;
    #pragma unroll
    for (int nt = 0; nt < 8; ++nt) {
      int col = nt*16 + lid;
      float cb1 = cb1sh[col], c2 = c2sh[col];
      #pragma unroll
      for (int mt = 0; mt < 2; ++mt)
        #pragma unroll
        for (int e = 0; e < 4; ++e)
          pcw[mt][e] += silu_f(acc[mt][nt][e] + cb1) * c2;
    }
    #pragma unroll
    for (int d = 1; d < 16; d <<= 1) {
      #pragma unroll
      for (int mt = 0; mt < 2; ++mt)
        #pragma unroll
        for (int e = 0; e < 4; ++e) pcw[mt][e] += __shfl_xor(pcw[mt][e], d, 64);
    }
    #pragma unroll
    for (int mt = 0; mt < 2; ++mt)
      #pragma unroll
      for (int e = 0; e < 4; ++e) {
        int ce = c0 + mt*16 + lgrp*4 + e;
        float cw = pcw[mt][e] + cb2;
        float e0 = lr0 - locsh[ce*2], e1 = lr1 - locsh[ce*2+1];
        float r2 = e0*e0 + e1*e1;
        float s = cw * __builtin_amdgcn_rcpf(__builtin_amdgcn_sqrtf(r2) + 1.0f);
        agg0 += e0*s; agg1 += e1*s;
      }
  }
  // sum partials across the four 16-lane groups
  agg0 += __shfl_xor(agg0, 16, 64); agg0 += __shfl_xor(agg0, 32, 64);
  agg1 += __shfl_xor(agg1, 16, 64); agg1 += __shfl_xor(agg1, 32, 64);

  if (lane == 0) {
    float mu0 = baseo[r*2+0] + agg0;
    float mu1 = baseo[r*2+1] + agg1;
    float ls0 = log_std[0], ls1 = log_std[1];
    float e0 = eps[r*2+0], e1 = eps[r*2+1];
    const float C = 0.9189385332046727f; // 0.5*log(2*pi)
    out[r*4+0] = mu0 + __expf(ls0)*e0;
    out[r*4+1] = mu1 + __expf(ls1)*e1;
    out[r*4+2] = -0.5f*e0*e0 - ls0 - C;
    out[r*4+3] = -0.5f*e1*e1 - ls1 - C;
  }
}

extern "C" void kernel_launch(void* const* d_in, const int* in_sizes, int n_in,
                              void* d_out, int out_size, void* d_ws, size_t ws_size,
                              hipStream_t stream) {
  const float* obs      = (const float*)d_in[0];
  const float* eps      = (const float*)d_in[1];
  const float* embed_w  = (const float*)d_in[2];
  const float* embed_b  = (const float*)d_in[3];
  const float* edge_w1  = (const float*)d_in[4];
  const float* edge_b1  = (const float*)d_in[5];
  const float* edge_w2  = (const float*)d_in[6];
  const float* edge_b2  = (const float*)d_in[7];
  const float* coord_w1 = (const float*)d_in[8];
  const float* coord_b1 = (const float*)d_in[9];
  const float* coord_w2 = (const float*)d_in[10];
  const float* coord_b2 = (const float*)d_in[11];
  const float* velm_w1  = (const float*)d_in[12];
  const float* velm_b1  = (const float*)d_in[13];
  const float* velm_w2  = (const float*)d_in[14];
  const float* velm_b2  = (const float*)d_in[15];
  const float* mlp_w1   = (const float*)d_in[20];
  const float* mlp_b1   = (const float*)d_in[21];
  const float* mlp_w2   = (const float*)d_in[22];
  const float* mlp_b2   = (const float*)d_in[23];
  const float* mlp_w3   = (const float*)d_in[24];
  const float* mlp_b3   = (const float*)d_in[25];
  const float* log_std  = (const float*)d_in[26];
  char* ws = (char*)d_ws;
  float* out = (float*)d_out;

  // allow >64KB dynamic LDS for k_edge (host-side, idempotent, capture-safe)
  hipFuncSetAttribute((const void*)k_edge,
                      hipFuncAttributeMaxDynamicSharedMemorySize, L_TOTAL);

  hipLaunchKernelGGL(k_prep, dim3(128), dim3(128), 0, stream,
                     edge_w1, edge_w2, coord_w1, velm_w1, mlp_w1, mlp_w2, embed_w, ws);
  hipLaunchKernelGGL(k_node, dim3(128), dim3(256), 0, stream,
                     obs, embed_b, edge_b1, velm_b1, velm_w2, velm_b2,
                     mlp_b1, mlp_b2, mlp_w3, mlp_b3, ws);
  hipLaunchKernelGGL(k_edge, dim3(1024), dim3(512), L_TOTAL, stream,
                     obs, eps, edge_b2, coord_b1, coord_w2, coord_b2, log_std, ws, out);
}